// Round 7
// baseline (376.827 us; speedup 1.0000x reference)
//
#include <hip/hip_runtime.h>

#define OUT_F 4096   // compressed rows
#define IN_F  2048   // compressed cols
#define KLOG  4096   // logical k = 2*IN_F
#define NB    4096   // batch
typedef unsigned long long ull;
typedef ull ullx2 __attribute__((ext_vector_type(2)));

typedef __bf16 bf16x8 __attribute__((ext_vector_type(8)));
typedef short  s16x8  __attribute__((ext_vector_type(8)));
typedef float  f32x4  __attribute__((ext_vector_type(4)));

__device__ __forceinline__ unsigned short f2bf(float f) {
    unsigned int u = __float_as_uint(f);
    u += 0x7fffu + ((u >> 16) & 1u);
    return (unsigned short)(u >> 16);
}

__device__ __forceinline__ void gload_lds16(const void* g, void* l) {
    __builtin_amdgcn_global_load_lds(
        (const __attribute__((address_space(1))) unsigned int*)g,
        (__attribute__((address_space(3))) unsigned int*)l, 16, 0, 0);
}

__device__ __forceinline__ bf16x8 ldsf(const char* p) {
    return __builtin_bit_cast(bf16x8, *(const s16x8*)p);
}

__device__ __forceinline__ bf16x8 gldf(const unsigned short* p) {
    return __builtin_bit_cast(bf16x8, *(const s16x8*)p);
}

#define MFMA16(a, b, c) __builtin_amdgcn_mfma_f32_16x16x32_bf16((a), (b), (c), 0, 0, 0)

// ---------- Pre-pass ----------
// blocks [0,8192): decompress weight -> wsA in MFMA-FRAGMENT-LINEAR order:
//   frag (R = row/16, Kq = k/32): ushort offset = (R*128 + Kq)*512 + lane*8,
//   lane l holds A[16R + (l&15)][32Kq + (l>>4)*8 .. +8]  (the 16x16x32 A-frag layout).
//   -> GEMM reads one A-frag as a fully coalesced 1 KB global_load_dwordx4.
// blocks [8192,12288): input f32 -> bf16 wsB (linear, for LDS staging), unchanged.
__global__ __launch_bounds__(256) void prep_kernel(
    const float* __restrict__ weight, const int* __restrict__ metadata,
    const float* __restrict__ input,
    unsigned short* __restrict__ wsA, unsigned short* __restrict__ wsB)
{
    const int b = blockIdx.x;
    if (b < 8192) {
        const int R    = b >> 5;                    // 0..255 (16-row tile)
        const int lane = threadIdx.x & 63;
        const int Kq   = ((b & 31) << 2) + (threadIdx.x >> 6);  // 0..127 (32-k tile)
        const int row  = (R << 4) + (lane & 15);
        const int kl0  = (Kq << 5) + (lane >> 4) * 8;  // logical k of this 8-elem chunk
        const int cc   = kl0 >> 1;                     // compressed col (mult of 4)
        const size_t off = (size_t)row * IN_F + cc;
        const float4 w = *(const float4*)(weight + off);
        const int4  md = *(const int4*)(metadata + off);
        // compressed pair (cc,cc+1) -> logical [kl0, kl0+4); (cc+2,cc+3) -> [kl0+4, kl0+8)
        ullx2 v;
        v.x = ((ull)f2bf(w.x) << (md.x * 16)) | ((ull)f2bf(w.y) << (md.y * 16));
        v.y = ((ull)f2bf(w.z) << (md.z * 16)) | ((ull)f2bf(w.w) << (md.w * 16));
        *(ullx2*)(wsA + ((size_t)(R * 128 + Kq) * 64 + lane) * 8) = v;
    } else {
        const int g = (b - 8192) * 256 + threadIdx.x;
        const size_t off = (size_t)g * 16;
        const float4 f0 = *(const float4*)(input + off);
        const float4 f1 = *(const float4*)(input + off + 4);
        const float4 f2 = *(const float4*)(input + off + 8);
        const float4 f3 = *(const float4*)(input + off + 12);
        ullx2 v01, v23;
        v01.x =  (ull)f2bf(f0.x) | ((ull)f2bf(f0.y) << 16) | ((ull)f2bf(f0.z) << 32) | ((ull)f2bf(f0.w) << 48);
        v01.y =  (ull)f2bf(f1.x) | ((ull)f2bf(f1.y) << 16) | ((ull)f2bf(f1.z) << 32) | ((ull)f2bf(f1.w) << 48);
        v23.x =  (ull)f2bf(f2.x) | ((ull)f2bf(f2.y) << 16) | ((ull)f2bf(f2.z) << 32) | ((ull)f2bf(f2.w) << 48);
        v23.y =  (ull)f2bf(f3.x) | ((ull)f2bf(f3.y) << 16) | ((ull)f2bf(f3.z) << 32) | ((ull)f2bf(f3.w) << 48);
        ull* dst = (ull*)(wsB + off);
        *(ullx2*)(dst)     = v01;
        *(ullx2*)(dst + 2) = v23;
    }
}

// ---------- Main GEMM: 256x256 tile, 8 waves (2M x 4N), BK=32, 16x16x32 bf16 MFMA.
// A-DIRECT: A fragments load global->VGPR (coalesced 1 KB, L2-resident via XCD swizzle),
// double-buffered one tile ahead (aP/aQ). LDS holds only the B ring (4 x 16 KB = 64 KB):
// DS traffic drops 3x (was 96 KB reads + 32 KB writes per tile/CU; now 32+16), so the
// DS pipe can no longer serialize against the 1242-cy MFMA burst; A's traffic rides the
// independent VMEM/L2 pipe under the MFMA shadow, drained by counted vmcnt(2).
// B staging map + swizzle (0 bank conflicts, R6-verified) carried over verbatim.
__global__ __launch_bounds__(512, 2) void gemm_kernel256(
    const unsigned short* __restrict__ wsA,   // fragment-ordered
    const unsigned short* __restrict__ wsB,
    const int* __restrict__ indices, float* __restrict__ out)
{
    __shared__ __align__(16) char lds[4 * 16384];   // B ring only

    const int tid  = threadIdx.x;
    const int lane = tid & 63;
    const int wave = tid >> 6;
    const int wm   = wave >> 2;   // 0..1 : 128-row half of the M-tile
    const int wn   = wave & 3;    // 0..3 : 64-col strip of the N-tile
    const int l15  = lane & 15;
    const int quad = lane >> 4;   // 0..3 : k-chunk of fragment

    // XCD swizzle: XCD x gets 32 consecutive tile ids = 2 A-panels (4 MB = its L2).
    const int swz = ((blockIdx.x & 7) << 5) | (blockIdx.x >> 3);
    const int r0 = (swz >> 4) << 8;   // M origin
    const int b0 = (swz & 15) << 8;   // N origin

    // ---- B staging (verified map): LDS byte tid*16 -> row tid>>2, phys chunk tid&3;
    //      source logical chunk = phys ^ ((row>>1)&3) ----
    const int srow   = tid >> 2;
    const int schunk = (tid & 3) ^ ((tid >> 3) & 3);
    const unsigned short* gB = wsB + (size_t)(b0 + srow) * KLOG + schunk * 8;

    // ---- B fragment-read constants (R6-verified, 0 conflicts) ----
    const unsigned xq    = (unsigned)((quad ^ ((l15 >> 1) & 3)) * 16);
    const unsigned bBase = (unsigned)((wn * 64 + l15) * 64);

    // ---- A fragment global base: frag (R, t) at ushort (R*128 + t)*512 + lane*8 ----
    const unsigned short* aBase = wsA
        + (size_t)((r0 >> 4) + wm * 8) * 128 * 512 + (unsigned)lane * 8;
    // rg stride = 65536 ushorts (128 KB), t stride = 512 ushorts (1 KB)

    f32x4 acc[8][4];
#pragma unroll
    for (int i = 0; i < 8; ++i)
#pragma unroll
        for (int j = 0; j < 4; ++j) acc[i][j] = (f32x4){0.f, 0.f, 0.f, 0.f};

    bf16x8 aP[8], aQ[8];

#define STAGE_B(t_) do { \
        char* _d = lds + (((t_) & 3) * 16384) + wave * 1024; \
        const unsigned short* _s = gB + (t_) * 32; \
        gload_lds16(_s, _d); \
        gload_lds16(_s + (size_t)128 * KLOG, _d + 8192); } while (0)

#define LOADA(D, t_) do { \
        const unsigned short* _p = aBase + (size_t)(t_) * 512; \
        D[0] = gldf(_p); \
        D[1] = gldf(_p + 1 * 65536); \
        D[2] = gldf(_p + 2 * 65536); \
        D[3] = gldf(_p + 3 * 65536); \
        D[4] = gldf(_p + 4 * 65536); \
        D[5] = gldf(_p + 5 * 65536); \
        D[6] = gldf(_p + 6 * 65536); \
        D[7] = gldf(_p + 7 * 65536); } while (0)

#define BAR()     __builtin_amdgcn_s_barrier()
#define SCHED0()  __builtin_amdgcn_sched_barrier(0)

    // one tile: A(t+1) global->reg issue, B(t+3) stage issue, B(t) ds_reads, 32 MFMA.
    // vmcnt FIFO (A first, stage second every tile): at end-of-t outstanding
    // [S(t+2)2, A(t+1)8, S(t+3)2] -> vmcnt(2) drains S(t+2)+A(t+1), leaves S(t+3).
#define TILE(t_, CUR, NXT) do { \
        if ((t_) < 127) LOADA(NXT, (t_) + 1); \
        if ((t_) < 125) STAGE_B((t_) + 3); \
        const char* pB = lds + ((unsigned)((t_) & 3)) * 16384u + bBase; \
        bf16x8 bf0 = ldsf(pB + xq); \
        bf16x8 bf1 = ldsf(pB + 1024 + xq); \
        bf16x8 bf2 = ldsf(pB + 2048 + xq); \
        bf16x8 bf3 = ldsf(pB + 3072 + xq); \
        SCHED0(); \
        __builtin_amdgcn_s_setprio(1); \
        acc[0][0] = MFMA16(CUR[0], bf0, acc[0][0]); \
        acc[0][1] = MFMA16(CUR[0], bf1, acc[0][1]); \
        acc[0][2] = MFMA16(CUR[0], bf2, acc[0][2]); \
        acc[0][3] = MFMA16(CUR[0], bf3, acc[0][3]); \
        acc[1][0] = MFMA16(CUR[1], bf0, acc[1][0]); \
        acc[1][1] = MFMA16(CUR[1], bf1, acc[1][1]); \
        acc[1][2] = MFMA16(CUR[1], bf2, acc[1][2]); \
        acc[1][3] = MFMA16(CUR[1], bf3, acc[1][3]); \
        acc[2][0] = MFMA16(CUR[2], bf0, acc[2][0]); \
        acc[2][1] = MFMA16(CUR[2], bf1, acc[2][1]); \
        acc[2][2] = MFMA16(CUR[2], bf2, acc[2][2]); \
        acc[2][3] = MFMA16(CUR[2], bf3, acc[2][3]); \
        acc[3][0] = MFMA16(CUR[3], bf0, acc[3][0]); \
        acc[3][1] = MFMA16(CUR[3], bf1, acc[3][1]); \
        acc[3][2] = MFMA16(CUR[3], bf2, acc[3][2]); \
        acc[3][3] = MFMA16(CUR[3], bf3, acc[3][3]); \
        acc[4][0] = MFMA16(CUR[4], bf0, acc[4][0]); \
        acc[4][1] = MFMA16(CUR[4], bf1, acc[4][1]); \
        acc[4][2] = MFMA16(CUR[4], bf2, acc[4][2]); \
        acc[4][3] = MFMA16(CUR[4], bf3, acc[4][3]); \
        acc[5][0] = MFMA16(CUR[5], bf0, acc[5][0]); \
        acc[5][1] = MFMA16(CUR[5], bf1, acc[5][1]); \
        acc[5][2] = MFMA16(CUR[5], bf2, acc[5][2]); \
        acc[5][3] = MFMA16(CUR[5], bf3, acc[5][3]); \
        acc[6][0] = MFMA16(CUR[6], bf0, acc[6][0]); \
        acc[6][1] = MFMA16(CUR[6], bf1, acc[6][1]); \
        acc[6][2] = MFMA16(CUR[6], bf2, acc[6][2]); \
        acc[6][3] = MFMA16(CUR[6], bf3, acc[6][3]); \
        acc[7][0] = MFMA16(CUR[7], bf0, acc[7][0]); \
        acc[7][1] = MFMA16(CUR[7], bf1, acc[7][1]); \
        acc[7][2] = MFMA16(CUR[7], bf2, acc[7][2]); \
        acc[7][3] = MFMA16(CUR[7], bf3, acc[7][3]); \
        __builtin_amdgcn_s_setprio(0); \
        if ((t_) < 125) { asm volatile("s_waitcnt vmcnt(2)" ::: "memory"); } \
        else            { asm volatile("s_waitcnt vmcnt(0)" ::: "memory"); } \
        BAR(); \
        SCHED0(); } while (0)

    // ---- prologue: A(0) first, then stage B(0..2); vmcnt(4) drains A(0)+S(0) ----
    LOADA(aP, 0);
    STAGE_B(0); STAGE_B(1); STAGE_B(2);
    asm volatile("s_waitcnt vmcnt(4)" ::: "memory");
    BAR();
    SCHED0();

    for (int i = 0; i < 64; ++i) {
        const int ta = 2 * i, tb = 2 * i + 1;
        TILE(ta, aP, aQ);
        TILE(tb, aQ, aP);
    }
#undef STAGE_B
#undef LOADA
#undef BAR
#undef SCHED0
#undef TILE

    // epilogue: C/D (16x16): col = l15, row = quad*4 + e  [R6-verified]
#pragma unroll
    for (int rg = 0; rg < 8; ++rg) {
#pragma unroll
        for (int e = 0; e < 4; ++e) {
            const int rloc = wm * 128 + rg * 16 + quad * 4 + e;
            const int L = indices[r0 + rloc];
            const size_t base  = (size_t)L * NB;
            const size_t baseZ = (size_t)(L ^ 1) * NB;
#pragma unroll
            for (int cf = 0; cf < 4; ++cf) {
                const int col = b0 + wn * 64 + cf * 16 + l15;
                out[base  + col] = acc[rg][cf][e];
                out[baseZ + col] = 0.0f;
            }
        }
    }
}

// ---------- Fallback (round-1 fused kernel) if ws is too small ----------
__global__ __launch_bounds__(256) void spmm_dt_fallback(
    const float* __restrict__ weight, const int* __restrict__ indices,
    const int* __restrict__ metadata, const float* __restrict__ input,
    float* __restrict__ out)
{
    __shared__ __align__(16) unsigned short As[128][32];
    __shared__ __align__(16) unsigned short Bs[128][32];
    const int tid = threadIdx.x, lane = tid & 63, wave = tid >> 6;
    const int wm = wave >> 1, wn = wave & 1, l15 = lane & 15, quad = lane >> 4;
    const int r0 = blockIdx.y * 128, b0 = blockIdx.x * 128;
    f32x4 acc[4][4];
#pragma unroll
    for (int i = 0; i < 4; ++i)
#pragma unroll
        for (int j = 0; j < 4; ++j) acc[i][j] = (f32x4){0.f, 0.f, 0.f, 0.f};
    const int srow = tid >> 3, sgrp = tid & 7;
    for (int kk = 0; kk < KLOG / 32; ++kk) {
        const int c0 = kk * 16, k0 = kk * 32;
#pragma unroll
        for (int s = 0; s < 4; ++s) {
            const int row = srow + s * 32;
            const size_t off = (size_t)(r0 + row) * IN_F + c0 + 2 * sgrp;
            const float2 w = *(const float2*)(weight + off);
            const int2  md = *(const int2*)(metadata + off);
            *(ull*)(&As[row][4 * sgrp]) =
                ((ull)f2bf(w.x) << (md.x * 16)) | ((ull)f2bf(w.y) << (md.y * 16));
        }
#pragma unroll
        for (int s = 0; s < 4; ++s) {
            const int row = srow + s * 32;
            const float4 f = *(const float4*)(&input[(size_t)(b0 + row) * KLOG + k0 + sgrp * 4]);
            *(ull*)(&Bs[row][sgrp * 4]) =
                 (ull)f2bf(f.x) | ((ull)f2bf(f.y) << 16) |
                ((ull)f2bf(f.z) << 32) | ((ull)f2bf(f.w) << 48);
        }
        __syncthreads();
        bf16x8 a[4], b[4];
#pragma unroll
        for (int i = 0; i < 4; ++i)
            a[i] = __builtin_bit_cast(bf16x8, *(const s16x8*)(&As[wm * 64 + i * 16 + l15][quad * 8]));
#pragma unroll
        for (int j = 0; j < 4; ++j)
            b[j] = __builtin_bit_cast(bf16x8, *(const s16x8*)(&Bs[wn * 64 + j * 16 + l15][quad * 8]));
#pragma unroll
        for (int i = 0; i < 4; ++i)
#pragma unroll
            for (int j = 0; j < 4; ++j)
                acc[i][j] = __builtin_amdgcn_mfma_f32_16x16x32_bf16(a[i], b[j], acc[i][j], 0, 0, 0);
        __syncthreads();
    }
#pragma unroll
    for (int i = 0; i < 4; ++i)
#pragma unroll
        for (int t = 0; t < 4; ++t) {
            const int r = r0 + wm * 64 + i * 16 + quad * 4 + t;
            const int L = indices[r];
            const size_t base = (size_t)L * NB, baseZ = (size_t)(L ^ 1) * NB;
#pragma unroll
            for (int j = 0; j < 4; ++j) {
                const int col = b0 + wn * 64 + j * 16 + l15;
                out[base + col] = acc[i][j][t];
                out[baseZ + col] = 0.0f;
            }
        }
}

extern "C" void kernel_launch(void* const* d_in, const int* in_sizes, int n_in,
                              void* d_out, int out_size, void* d_ws, size_t ws_size,
                              hipStream_t stream) {
    const float* weight   = (const float*)d_in[0];
    const int*   indices  = (const int*)d_in[1];
    const int*   metadata = (const int*)d_in[2];
    const float* input    = (const float*)d_in[3];
    float*       out      = (float*)d_out;

    const size_t needA = (size_t)OUT_F * KLOG * 2;  // 32 MB (fragment-ordered)
    const size_t needB = (size_t)NB * KLOG * 2;     // 32 MB
    if (ws_size >= needA + needB) {
        unsigned short* wsA = (unsigned short*)d_ws;
        unsigned short* wsB = wsA + (size_t)OUT_F * KLOG;
        prep_kernel<<<dim3(12288), dim3(256), 0, stream>>>(weight, metadata, input, wsA, wsB);
        gemm_kernel256<<<dim3(256), dim3(512), 0, stream>>>(wsA, wsB, indices, out);
    } else {
        spmm_dt_fallback<<<dim3(NB / 128, OUT_F / 128), dim3(256), 0, stream>>>(
            weight, indices, metadata, input, out);
    }
}